// Round 1
// baseline (14609.641 us; speedup 1.0000x reference)
//
#include <hip/hip_runtime.h>
#include <hip/hip_bf16.h>

#define BB 4096
#define INF 8192
#define SS 128
#define DD 64
#define HH 256

__device__ __forceinline__ float sigm(float x) { return 1.f / (1.f + __expf(-x)); }
__device__ __forceinline__ float tanh_fast(float x) {
    float cx = fminf(15.f, fmaxf(-15.f, x));
    float e = __expf(2.f * cx);
    return (e - 1.f) / (e + 1.f);
}

// ---- BatchNorm stats: column sums over the batch -------------------------
__global__ __launch_bounds__(256) void bn_partial(const float* __restrict__ x,
                                                  float* __restrict__ colsum,
                                                  float* __restrict__ colsumsq) {
    int j = blockIdx.x * 256 + threadIdx.x;
    int r0 = blockIdx.y * 256;
    float s1 = 0.f, s2 = 0.f;
    for (int r = r0; r < r0 + 256; ++r) {
        float v = x[(size_t)r * INF + j];
        s1 += v;
        s2 += v * v;
    }
    atomicAdd(&colsum[j], s1);
    atomicAdd(&colsumsq[j], s2);
}

__global__ __launch_bounds__(256) void bn_finalize(const float* __restrict__ colsum,
                                                   const float* __restrict__ colsumsq,
                                                   const float* __restrict__ gamma,
                                                   const float* __restrict__ beta,
                                                   float* __restrict__ scl,
                                                   float* __restrict__ shf) {
    int j = blockIdx.x * 256 + threadIdx.x;
    float mean = colsum[j] * (1.f / BB);
    float var = colsumsq[j] * (1.f / BB) - mean * mean;
    float a = gamma[j] * rsqrtf(var + 1e-5f);
    scl[j] = a;
    shf[j] = beta[j] - mean * a;
}

// ---- proj = (x*scl+shf) @ W_in^T : M=4096 N=8192 K=8192, NT, fp32 --------
// 128x128 tile, BK=16, 256 threads, 8x8 per thread.
__global__ __launch_bounds__(256) void gemm_proj_f32(const float* __restrict__ x,
                                                     const float* __restrict__ scl,
                                                     const float* __restrict__ shf,
                                                     const float* __restrict__ W,
                                                     float* __restrict__ C) {
    __shared__ float As[16][132];
    __shared__ float Bs[16][132];
    const int tid = threadIdx.x;
    const int tx = tid & 15, ty = tid >> 4;
    const int row0 = blockIdx.y << 7;
    const int col0 = blockIdx.x << 7;
    const int lr = tid >> 1;
    const int lk = (tid & 1) << 3;

    float acc[8][8];
#pragma unroll
    for (int i = 0; i < 8; ++i)
#pragma unroll
        for (int j = 0; j < 8; ++j) acc[i][j] = 0.f;

    const float* xrow = x + (size_t)(row0 + lr) * INF + lk;
    const float* wrow = W + (size_t)(col0 + lr) * INF + lk;

    for (int kb = 0; kb < INF / 16; ++kb) {
        const int k0 = kb << 4;
        float4 a0 = *(const float4*)(xrow + k0);
        float4 a1 = *(const float4*)(xrow + k0 + 4);
        float4 s0 = *(const float4*)(scl + k0 + lk);
        float4 s1 = *(const float4*)(scl + k0 + lk + 4);
        float4 h0 = *(const float4*)(shf + k0 + lk);
        float4 h1 = *(const float4*)(shf + k0 + lk + 4);
        float4 b0 = *(const float4*)(wrow + k0);
        float4 b1 = *(const float4*)(wrow + k0 + 4);
        float av[8] = {fmaf(a0.x, s0.x, h0.x), fmaf(a0.y, s0.y, h0.y),
                       fmaf(a0.z, s0.z, h0.z), fmaf(a0.w, s0.w, h0.w),
                       fmaf(a1.x, s1.x, h1.x), fmaf(a1.y, s1.y, h1.y),
                       fmaf(a1.z, s1.z, h1.z), fmaf(a1.w, s1.w, h1.w)};
        float bv[8] = {b0.x, b0.y, b0.z, b0.w, b1.x, b1.y, b1.z, b1.w};
        __syncthreads();
#pragma unroll
        for (int i = 0; i < 8; ++i) {
            As[lk + i][lr] = av[i];
            Bs[lk + i][lr] = bv[i];
        }
        __syncthreads();
#pragma unroll
        for (int k = 0; k < 16; ++k) {
            float4 aa0 = *(const float4*)&As[k][ty << 3];
            float4 aa1 = *(const float4*)&As[k][(ty << 3) + 4];
            float4 bb0 = *(const float4*)&Bs[k][tx << 2];
            float4 bb1 = *(const float4*)&Bs[k][64 + (tx << 2)];
            float ar[8] = {aa0.x, aa0.y, aa0.z, aa0.w, aa1.x, aa1.y, aa1.z, aa1.w};
            float br[8] = {bb0.x, bb0.y, bb0.z, bb0.w, bb1.x, bb1.y, bb1.z, bb1.w};
#pragma unroll
            for (int i = 0; i < 8; ++i)
#pragma unroll
                for (int j = 0; j < 8; ++j)
                    acc[i][j] = fmaf(ar[i], br[j], acc[i][j]);
        }
    }
#pragma unroll
    for (int i = 0; i < 8; ++i) {
        float* crow = C + (size_t)(row0 + (ty << 3) + i) * INF + col0;
        float4 o0 = {acc[i][0], acc[i][1], acc[i][2], acc[i][3]};
        float4 o1 = {acc[i][4], acc[i][5], acc[i][6], acc[i][7]};
        *(float4*)(crow + (tx << 2)) = o0;
        *(float4*)(crow + 64 + (tx << 2)) = o1;
    }
}

// ---- one LSTM step: gates GEMM (K=64 from proj slice + K=256 from h) fused
// with the cell nonlinearity. Block computes 64 batch rows x 64 h-cols x 4 gates.
__global__ __launch_bounds__(256) void lstm_step(const float* __restrict__ proj,
                                                 const float* __restrict__ W_ih,
                                                 const float* __restrict__ W_hh,
                                                 const float* __restrict__ b_ih,
                                                 const float* __restrict__ b_hh,
                                                 float* __restrict__ cbuf,
                                                 float* __restrict__ hs, int s) {
    __shared__ float As[16][68];
    __shared__ float Bs[4][16][68];
    __shared__ float sb[4][64];
    const int tid = threadIdx.x;
    const int tx = tid & 15, ty = tid >> 4;
    const int row0 = blockIdx.y << 6;  // batch
    const int c0 = blockIdx.x << 6;    // hidden col
    {
        int g = tid >> 6, cc = tid & 63;
        sb[g][cc] = b_ih[g * 256 + c0 + cc] + b_hh[g * 256 + c0 + cc];
    }
    const int lr = tid >> 2;
    const int lk = (tid & 3) << 2;

    float acc[4][4][4];
#pragma unroll
    for (int g = 0; g < 4; ++g)
#pragma unroll
        for (int i = 0; i < 4; ++i)
#pragma unroll
            for (int j = 0; j < 4; ++j) acc[g][i][j] = 0.f;

    const float* hprev = hs + (size_t)(s - 1) * BB * HH;

    for (int kb = 0; kb < 20; ++kb) {
        float4 av;
        float4 bv[4];
        if (kb < 4) {
            av = *(const float4*)(proj + (size_t)(row0 + lr) * INF + s * 64 + (kb << 4) + lk);
#pragma unroll
            for (int g = 0; g < 4; ++g)
                bv[g] = *(const float4*)(W_ih + (size_t)(g * 256 + c0 + lr) * 64 + (kb << 4) + lk);
        } else {
            int kh = (kb << 4) - 64 + lk;
            if (s > 0)
                av = *(const float4*)(hprev + (size_t)(row0 + lr) * HH + kh);
            else
                av = make_float4(0.f, 0.f, 0.f, 0.f);
#pragma unroll
            for (int g = 0; g < 4; ++g)
                bv[g] = *(const float4*)(W_hh + (size_t)(g * 256 + c0 + lr) * 256 + kh);
        }
        __syncthreads();
#pragma unroll
        for (int i = 0; i < 4; ++i) {
            As[lk + i][lr] = ((const float*)&av)[i];
#pragma unroll
            for (int g = 0; g < 4; ++g) Bs[g][lk + i][lr] = ((const float*)&bv[g])[i];
        }
        __syncthreads();
#pragma unroll
        for (int k = 0; k < 16; ++k) {
            float4 af = *(const float4*)&As[k][ty << 2];
            float ar[4] = {af.x, af.y, af.z, af.w};
#pragma unroll
            for (int g = 0; g < 4; ++g) {
                float4 bf = *(const float4*)&Bs[g][k][tx << 2];
                float br[4] = {bf.x, bf.y, bf.z, bf.w};
#pragma unroll
                for (int i = 0; i < 4; ++i)
#pragma unroll
                    for (int j = 0; j < 4; ++j)
                        acc[g][i][j] = fmaf(ar[i], br[j], acc[g][i][j]);
            }
        }
    }
    // fused cell update epilogue
#pragma unroll
    for (int i = 0; i < 4; ++i) {
        int b = row0 + (ty << 2) + i;
        size_t cidx = (size_t)b * HH + c0 + (tx << 2);
        float co[4];
        if (s > 0)
            *(float4*)co = *(const float4*)(cbuf + cidx);
        else {
            co[0] = co[1] = co[2] = co[3] = 0.f;
        }
        float cn[4], hn[4];
#pragma unroll
        for (int j = 0; j < 4; ++j) {
            int cc = (tx << 2) + j;
            float ig = sigm(acc[0][i][j] + sb[0][cc]);
            float fg = sigm(acc[1][i][j] + sb[1][cc]);
            float gg = tanh_fast(acc[2][i][j] + sb[2][cc]);
            float og = sigm(acc[3][i][j] + sb[3][cc]);
            float c2 = fmaf(fg, co[j], ig * gg);
            cn[j] = c2;
            hn[j] = og * tanh_fast(c2);
        }
        *(float4*)(cbuf + cidx) = *(float4*)cn;
        *(float4*)(hs + ((size_t)s * BB + b) * HH + c0 + (tx << 2)) = *(float4*)hn;
    }
}

// ---- q[b,s] = hs[s,b,:] . W_out  (one wave per (b,s)) --------------------
__global__ __launch_bounds__(256) void q_kernel(const float* __restrict__ hs,
                                                const float* __restrict__ wout,
                                                float* __restrict__ q) {
    int wid = threadIdx.x >> 6, lane = threadIdx.x & 63;
    int p = (blockIdx.x << 2) + wid;
    int b = p & (BB - 1), s = p >> 12;
    const float* hp = hs + ((size_t)s * BB + b) * HH + (lane << 2);
    float4 h4 = *(const float4*)hp;
    float4 w4 = *(const float4*)(wout + (lane << 2));
    float v = h4.x * w4.x + h4.y * w4.y + h4.z * w4.z + h4.w * w4.w;
#pragma unroll
    for (int off = 32; off; off >>= 1) v += __shfl_xor(v, off);
    if (lane == 0) q[b * SS + s] = v;
}

// ---- attention logits, split-K (8 chunks of K=4096): part[j][b][t] -------
__global__ __launch_bounds__(256) void attn_part(const float* __restrict__ hs,
                                                 const float* __restrict__ Wta,
                                                 float* __restrict__ part) {
    __shared__ float As[16][68];
    __shared__ float Bs[16][132];
    const int tid = threadIdx.x;
    const int tx = tid & 15, ty = tid >> 4;
    const int row0 = blockIdx.x << 6;
    const int jc = blockIdx.y;
    const int lrA = tid >> 2, lkA = (tid & 3) << 2;
    const int lrB = tid >> 1, lkB = (tid & 1) << 3;

    float acc[4][8];
#pragma unroll
    for (int i = 0; i < 4; ++i)
#pragma unroll
        for (int j = 0; j < 8; ++j) acc[i][j] = 0.f;

    for (int kb = 0; kb < 256; ++kb) {
        int k0 = (jc << 12) + (kb << 4);
        int sidx = k0 >> 8, h0 = k0 & 255;
        float4 av = *(const float4*)(hs + ((size_t)sidx * BB + row0 + lrA) * HH + h0 + lkA);
        const float* wp = Wta + (size_t)lrB * (SS * HH) + k0 + lkB;
        float4 bv0 = *(const float4*)wp;
        float4 bv1 = *(const float4*)(wp + 4);
        __syncthreads();
        As[lkA + 0][lrA] = av.x;
        As[lkA + 1][lrA] = av.y;
        As[lkA + 2][lrA] = av.z;
        As[lkA + 3][lrA] = av.w;
        Bs[lkB + 0][lrB] = bv0.x;
        Bs[lkB + 1][lrB] = bv0.y;
        Bs[lkB + 2][lrB] = bv0.z;
        Bs[lkB + 3][lrB] = bv0.w;
        Bs[lkB + 4][lrB] = bv1.x;
        Bs[lkB + 5][lrB] = bv1.y;
        Bs[lkB + 6][lrB] = bv1.z;
        Bs[lkB + 7][lrB] = bv1.w;
        __syncthreads();
#pragma unroll
        for (int k = 0; k < 16; ++k) {
            float4 af = *(const float4*)&As[k][ty << 2];
            float4 b0 = *(const float4*)&Bs[k][tx << 2];
            float4 b1 = *(const float4*)&Bs[k][64 + (tx << 2)];
            float ar[4] = {af.x, af.y, af.z, af.w};
            float br[8] = {b0.x, b0.y, b0.z, b0.w, b1.x, b1.y, b1.z, b1.w};
#pragma unroll
            for (int i = 0; i < 4; ++i)
#pragma unroll
                for (int j = 0; j < 8; ++j)
                    acc[i][j] = fmaf(ar[i], br[j], acc[i][j]);
        }
    }
#pragma unroll
    for (int i = 0; i < 4; ++i) {
        int b = row0 + (ty << 2) + i;
        float* pp = part + ((size_t)jc * BB + b) * SS;
        float4 o0 = {acc[i][0], acc[i][1], acc[i][2], acc[i][3]};
        float4 o1 = {acc[i][4], acc[i][5], acc[i][6], acc[i][7]};
        *(float4*)(pp + (tx << 2)) = o0;
        *(float4*)(pp + 64 + (tx << 2)) = o1;
    }
}

// ---- relu -> softmax -> weighted sum of q : one wave per batch row -------
__global__ __launch_bounds__(256) void attn_finalize(const float* __restrict__ part,
                                                     const float* __restrict__ b_ta,
                                                     const float* __restrict__ q,
                                                     float* __restrict__ out) {
    int wid = threadIdx.x >> 6, lane = threadIdx.x & 63;
    int b = (blockIdx.x << 2) + wid;
    float l0 = b_ta[lane], l1 = b_ta[lane + 64];
#pragma unroll
    for (int j = 0; j < 8; ++j) {
        const float* pp = part + ((size_t)j * BB + b) * SS;
        l0 += pp[lane];
        l1 += pp[lane + 64];
    }
    l0 = fmaxf(l0, 0.f);
    l1 = fmaxf(l1, 0.f);
    float mx = fmaxf(l0, l1);
#pragma unroll
    for (int off = 32; off; off >>= 1) mx = fmaxf(mx, __shfl_xor(mx, off));
    float e0 = __expf(l0 - mx), e1 = __expf(l1 - mx);
    float num = fmaf(e0, q[b * SS + lane], e1 * q[b * SS + lane + 64]);
    float den = e0 + e1;
#pragma unroll
    for (int off = 32; off; off >>= 1) {
        num += __shfl_xor(num, off);
        den += __shfl_xor(den, off);
    }
    if (lane == 0) out[b] = num / den;
}

extern "C" void kernel_launch(void* const* d_in, const int* in_sizes, int n_in,
                              void* d_out, int out_size, void* d_ws, size_t ws_size,
                              hipStream_t stream) {
    const float* x     = (const float*)d_in[0];
    const float* gamma = (const float*)d_in[1];
    const float* beta_ = (const float*)d_in[2];
    const float* W_in  = (const float*)d_in[3];
    const float* W_ih  = (const float*)d_in[4];
    const float* b_ih  = (const float*)d_in[5];
    const float* W_hh  = (const float*)d_in[6];
    const float* b_hh  = (const float*)d_in[7];
    const float* W_ta  = (const float*)d_in[8];
    const float* b_ta  = (const float*)d_in[9];
    const float* W_out = (const float*)d_in[10];
    float* out = (float*)d_out;

    float* ws = (float*)d_ws;
    float* colsum   = ws;                       // 8192
    float* colsumsq = ws + 8192;                // 8192
    float* scl      = ws + 16384;               // 8192
    float* shf      = ws + 24576;               // 8192
    float* proj     = ws + 32768;               // 4096*8192   = 33,554,432
    float* cbuf     = proj + 33554432;          // 4096*256    = 1,048,576
    float* hs       = cbuf + 1048576;           // 128*4096*256= 134,217,728
    float* q        = hs + 134217728;           // 4096*128    = 524,288
    float* part     = q + 524288;               // 8*4096*128  = 4,194,304

    hipMemsetAsync(colsum, 0, 2 * 8192 * sizeof(float), stream);
    bn_partial<<<dim3(32, 16), 256, 0, stream>>>(x, colsum, colsumsq);
    bn_finalize<<<32, 256, 0, stream>>>(colsum, colsumsq, gamma, beta_, scl, shf);
    gemm_proj_f32<<<dim3(64, 32), 256, 0, stream>>>(x, scl, shf, W_in, proj);
    for (int s = 0; s < 128; ++s)
        lstm_step<<<dim3(4, 64), 256, 0, stream>>>(proj, W_ih, W_hh, b_ih, b_hh, cbuf, hs, s);
    q_kernel<<<131072, 256, 0, stream>>>(hs, W_out, q);
    attn_part<<<dim3(64, 8), 256, 0, stream>>>(hs, W_ta, part);
    attn_finalize<<<1024, 256, 0, stream>>>(part, b_ta, q, out);
}

// Round 2
// 10145.157 us; speedup vs baseline: 1.4401x; 1.4401x over previous
//
#include <hip/hip_runtime.h>
#include <hip/hip_bf16.h>

#define BB 4096
#define INF 8192
#define SS 128
#define HH 256

typedef __attribute__((ext_vector_type(8))) short short8;
typedef __attribute__((ext_vector_type(4))) float f32x4;

__device__ __forceinline__ float sigm(float x) { return 1.f / (1.f + __expf(-x)); }
__device__ __forceinline__ float tanh_fast(float x) {
    float cx = fminf(15.f, fmaxf(-15.f, x));
    float e = __expf(2.f * cx);
    return (e - 1.f) / (e + 1.f);
}

__device__ __forceinline__ unsigned short f2bf(float f) {
    __hip_bfloat16 b = __float2bfloat16(f);
    return *(unsigned short*)&b;
}
__device__ __forceinline__ float bf2f(unsigned short u) {
    __hip_bfloat16 b = *(__hip_bfloat16*)&u;
    return __bfloat162float(b);
}

// ---- BatchNorm stats: column sums over the batch -------------------------
__global__ __launch_bounds__(256) void bn_partial(const float* __restrict__ x,
                                                  float* __restrict__ colsum,
                                                  float* __restrict__ colsumsq) {
    int j = blockIdx.x * 256 + threadIdx.x;
    int r0 = blockIdx.y * 256;
    float s1 = 0.f, s2 = 0.f;
    for (int r = r0; r < r0 + 256; ++r) {
        float v = x[(size_t)r * INF + j];
        s1 += v;
        s2 += v * v;
    }
    atomicAdd(&colsum[j], s1);
    atomicAdd(&colsumsq[j], s2);
}

__global__ __launch_bounds__(256) void bn_finalize(const float* __restrict__ colsum,
                                                   const float* __restrict__ colsumsq,
                                                   const float* __restrict__ gamma,
                                                   const float* __restrict__ beta,
                                                   float* __restrict__ scl,
                                                   float* __restrict__ shf) {
    int j = blockIdx.x * 256 + threadIdx.x;
    float mean = colsum[j] * (1.f / BB);
    float var = colsumsq[j] * (1.f / BB) - mean * mean;
    float a = gamma[j] * rsqrtf(var + 1e-5f);
    scl[j] = a;
    shf[j] = beta[j] - mean * a;
}

// ---- split fp32 -> bf16 hi/lo, with optional affine (BN fuse) ------------
__global__ __launch_bounds__(256) void split_x(const float* __restrict__ x,
                                               const float* __restrict__ scl,
                                               const float* __restrict__ shf,
                                               unsigned short* __restrict__ hi,
                                               unsigned short* __restrict__ lo) {
    size_t i = ((size_t)blockIdx.x * 256 + threadIdx.x) * 4;
    float4 v = *(const float4*)(x + i);
    int col = (int)(i & (INF - 1));
    float4 s = *(const float4*)(scl + col);
    float4 h = *(const float4*)(shf + col);
    float f[4] = {fmaf(v.x, s.x, h.x), fmaf(v.y, s.y, h.y),
                  fmaf(v.z, s.z, h.z), fmaf(v.w, s.w, h.w)};
    ushort4 hv, lv;
    unsigned short* hp = (unsigned short*)&hv;
    unsigned short* lp = (unsigned short*)&lv;
#pragma unroll
    for (int k = 0; k < 4; ++k) {
        unsigned short hb = f2bf(f[k]);
        hp[k] = hb;
        lp[k] = f2bf(f[k] - bf2f(hb));
    }
    *(ushort4*)(hi + i) = hv;
    *(ushort4*)(lo + i) = lv;
}

__global__ __launch_bounds__(256) void split_w(const float* __restrict__ w,
                                               unsigned short* __restrict__ hi,
                                               unsigned short* __restrict__ lo) {
    size_t i = ((size_t)blockIdx.x * 256 + threadIdx.x) * 4;
    float4 v = *(const float4*)(w + i);
    float f[4] = {v.x, v.y, v.z, v.w};
    ushort4 hv, lv;
    unsigned short* hp = (unsigned short*)&hv;
    unsigned short* lp = (unsigned short*)&lv;
#pragma unroll
    for (int k = 0; k < 4; ++k) {
        unsigned short hb = f2bf(f[k]);
        hp[k] = hb;
        lp[k] = f2bf(f[k] - bf2f(hb));
    }
    *(ushort4*)(hi + i) = hv;
    *(ushort4*)(lo + i) = lv;
}

// ---- C[M][N] = A[M][K] @ B[N][K]^T via split-bf16 MFMA -------------------
// 128x128 tile, BK=32, 4 waves, each wave 64x64 (4x4 frags of 16x16x32).
// 3 MFMAs per frag pair: Ah*Bh + Ah*Bl + Al*Bh (~2^-17 rel error).
__global__ __launch_bounds__(256) void gemm_mfma_split(
    const unsigned short* __restrict__ Ah, const unsigned short* __restrict__ Al,
    const unsigned short* __restrict__ Bh, const unsigned short* __restrict__ Bl,
    float* __restrict__ C, int M, int N, int K) {
    __shared__ unsigned short As[2][128 * 32];
    __shared__ unsigned short Bs[2][128 * 32];
    const int tid = threadIdx.x;
    const int lane = tid & 63, wid = tid >> 6;
    const int row0 = blockIdx.y << 7, col0 = blockIdx.x << 7;
    const int wm = (wid & 1) << 6, wn = (wid >> 1) << 6;

    // staging: 512 16B segments per tile; wave wid stages segs [wid*128, wid*128+128)
    const int seg0 = wid * 128 + lane;
    const int seg1 = seg0 + 64;
    const int r0s = seg0 >> 2, c0s = (seg0 & 3) << 3;
    const int r1s = seg1 >> 2, c1s = (seg1 & 3) << 3;
    const size_t aoff0 = (size_t)(row0 + r0s) * K + c0s;
    const size_t aoff1 = (size_t)(row0 + r1s) * K + c1s;
    const size_t boff0 = (size_t)(col0 + r0s) * K + c0s;
    const size_t boff1 = (size_t)(col0 + r1s) * K + c1s;
    const int ldsbase0 = (wid * 128) * 8;  // ushort index of wave's first segment
    const int ldsbase1 = ldsbase0 + 64 * 8;

    f32x4 acc[4][4];
#pragma unroll
    for (int i = 0; i < 4; ++i)
#pragma unroll
        for (int j = 0; j < 4; ++j) acc[i][j] = (f32x4){0.f, 0.f, 0.f, 0.f};

    const int q = lane >> 4, l15 = lane & 15;

    for (int kb = 0; kb < K; kb += 32) {
        __syncthreads();
#define GLD(g, l) __builtin_amdgcn_global_load_lds(                              \
        (const __attribute__((address_space(1))) void*)(g),                      \
        (__attribute__((address_space(3))) void*)(l), 16, 0, 0)
        GLD(Ah + aoff0 + kb, &As[0][ldsbase0]);
        GLD(Ah + aoff1 + kb, &As[0][ldsbase1]);
        GLD(Al + aoff0 + kb, &As[1][ldsbase0]);
        GLD(Al + aoff1 + kb, &As[1][ldsbase1]);
        GLD(Bh + boff0 + kb, &Bs[0][ldsbase0]);
        GLD(Bh + boff1 + kb, &Bs[0][ldsbase1]);
        GLD(Bl + boff0 + kb, &Bs[1][ldsbase0]);
        GLD(Bl + boff1 + kb, &Bs[1][ldsbase1]);
#undef GLD
        __syncthreads();

        short8 ahf[4], alf[4], bhf[4], blf[4];
#pragma unroll
        for (int i = 0; i < 4; ++i) {
            int offa = (wm + i * 16 + l15) * 32 + q * 8;
            ahf[i] = *(const short8*)&As[0][offa];
            alf[i] = *(const short8*)&As[1][offa];
            int offb = (wn + i * 16 + l15) * 32 + q * 8;
            bhf[i] = *(const short8*)&Bs[0][offb];
            blf[i] = *(const short8*)&Bs[1][offb];
        }
#pragma unroll
        for (int i = 0; i < 4; ++i)
#pragma unroll
            for (int j = 0; j < 4; ++j) {
                acc[i][j] = __builtin_amdgcn_mfma_f32_16x16x32_bf16(ahf[i], bhf[j], acc[i][j], 0, 0, 0);
                acc[i][j] = __builtin_amdgcn_mfma_f32_16x16x32_bf16(ahf[i], blf[j], acc[i][j], 0, 0, 0);
                acc[i][j] = __builtin_amdgcn_mfma_f32_16x16x32_bf16(alf[i], bhf[j], acc[i][j], 0, 0, 0);
            }
    }

#pragma unroll
    for (int i = 0; i < 4; ++i)
#pragma unroll
        for (int j = 0; j < 4; ++j) {
            int col = col0 + wn + j * 16 + l15;
#pragma unroll
            for (int r = 0; r < 4; ++r) {
                int row = row0 + wm + i * 16 + q * 4 + r;
                C[(size_t)row * N + col] = acc[i][j][r];
            }
        }
}

// ---- one LSTM step (unchanged from R1) -----------------------------------
__global__ __launch_bounds__(256) void lstm_step(const float* __restrict__ proj,
                                                 const float* __restrict__ W_ih,
                                                 const float* __restrict__ W_hh,
                                                 const float* __restrict__ b_ih,
                                                 const float* __restrict__ b_hh,
                                                 float* __restrict__ cbuf,
                                                 float* __restrict__ hs, int s) {
    __shared__ float As[16][68];
    __shared__ float Bs[4][16][68];
    __shared__ float sb[4][64];
    const int tid = threadIdx.x;
    const int tx = tid & 15, ty = tid >> 4;
    const int row0 = blockIdx.y << 6;
    const int c0 = blockIdx.x << 6;
    {
        int g = tid >> 6, cc = tid & 63;
        sb[g][cc] = b_ih[g * 256 + c0 + cc] + b_hh[g * 256 + c0 + cc];
    }
    const int lr = tid >> 2;
    const int lk = (tid & 3) << 2;

    float acc[4][4][4];
#pragma unroll
    for (int g = 0; g < 4; ++g)
#pragma unroll
        for (int i = 0; i < 4; ++i)
#pragma unroll
            for (int j = 0; j < 4; ++j) acc[g][i][j] = 0.f;

    const float* hprev = hs + (size_t)(s - 1) * BB * HH;

    for (int kb = 0; kb < 20; ++kb) {
        float4 av;
        float4 bv[4];
        if (kb < 4) {
            av = *(const float4*)(proj + (size_t)(row0 + lr) * INF + s * 64 + (kb << 4) + lk);
#pragma unroll
            for (int g = 0; g < 4; ++g)
                bv[g] = *(const float4*)(W_ih + (size_t)(g * 256 + c0 + lr) * 64 + (kb << 4) + lk);
        } else {
            int kh = (kb << 4) - 64 + lk;
            if (s > 0)
                av = *(const float4*)(hprev + (size_t)(row0 + lr) * HH + kh);
            else
                av = make_float4(0.f, 0.f, 0.f, 0.f);
#pragma unroll
            for (int g = 0; g < 4; ++g)
                bv[g] = *(const float4*)(W_hh + (size_t)(g * 256 + c0 + lr) * 256 + kh);
        }
        __syncthreads();
#pragma unroll
        for (int i = 0; i < 4; ++i) {
            As[lk + i][lr] = ((const float*)&av)[i];
#pragma unroll
            for (int g = 0; g < 4; ++g) Bs[g][lk + i][lr] = ((const float*)&bv[g])[i];
        }
        __syncthreads();
#pragma unroll
        for (int k = 0; k < 16; ++k) {
            float4 af = *(const float4*)&As[k][ty << 2];
            float ar[4] = {af.x, af.y, af.z, af.w};
#pragma unroll
            for (int g = 0; g < 4; ++g) {
                float4 bf = *(const float4*)&Bs[g][k][tx << 2];
                float br[4] = {bf.x, bf.y, bf.z, bf.w};
#pragma unroll
                for (int i = 0; i < 4; ++i)
#pragma unroll
                    for (int j = 0; j < 4; ++j)
                        acc[g][i][j] = fmaf(ar[i], br[j], acc[g][i][j]);
            }
        }
    }
#pragma unroll
    for (int i = 0; i < 4; ++i) {
        int b = row0 + (ty << 2) + i;
        size_t cidx = (size_t)b * HH + c0 + (tx << 2);
        float co[4];
        if (s > 0)
            *(float4*)co = *(const float4*)(cbuf + cidx);
        else {
            co[0] = co[1] = co[2] = co[3] = 0.f;
        }
        float cn[4], hn[4];
#pragma unroll
        for (int j = 0; j < 4; ++j) {
            int cc = (tx << 2) + j;
            float ig = sigm(acc[0][i][j] + sb[0][cc]);
            float fg = sigm(acc[1][i][j] + sb[1][cc]);
            float gg = tanh_fast(acc[2][i][j] + sb[2][cc]);
            float og = sigm(acc[3][i][j] + sb[3][cc]);
            float c2 = fmaf(fg, co[j], ig * gg);
            cn[j] = c2;
            hn[j] = og * tanh_fast(c2);
        }
        *(float4*)(cbuf + cidx) = *(float4*)cn;
        *(float4*)(hs + ((size_t)s * BB + b) * HH + c0 + (tx << 2)) = *(float4*)hn;
    }
}

// ---- q[b,s] = hs[s,b,:] . W_out  (one wave per (b,s)) --------------------
__global__ __launch_bounds__(256) void q_kernel(const float* __restrict__ hs,
                                                const float* __restrict__ wout,
                                                float* __restrict__ q) {
    int wid = threadIdx.x >> 6, lane = threadIdx.x & 63;
    int p = (blockIdx.x << 2) + wid;
    int b = p & (BB - 1), s = p >> 12;
    const float* hp = hs + ((size_t)s * BB + b) * HH + (lane << 2);
    float4 h4 = *(const float4*)hp;
    float4 w4 = *(const float4*)(wout + (lane << 2));
    float v = h4.x * w4.x + h4.y * w4.y + h4.z * w4.z + h4.w * w4.w;
#pragma unroll
    for (int off = 32; off; off >>= 1) v += __shfl_xor(v, off);
    if (lane == 0) q[b * SS + s] = v;
}

// ---- attention logits, split-K (8 chunks of K=4096): part[j][b][t] -------
__global__ __launch_bounds__(256) void attn_part(const float* __restrict__ hs,
                                                 const float* __restrict__ Wta,
                                                 float* __restrict__ part) {
    __shared__ float As[16][68];
    __shared__ float Bs[16][132];
    const int tid = threadIdx.x;
    const int tx = tid & 15, ty = tid >> 4;
    const int row0 = blockIdx.x << 6;
    const int jc = blockIdx.y;
    const int lrA = tid >> 2, lkA = (tid & 3) << 2;
    const int lrB = tid >> 1, lkB = (tid & 1) << 3;

    float acc[4][8];
#pragma unroll
    for (int i = 0; i < 4; ++i)
#pragma unroll
        for (int j = 0; j < 8; ++j) acc[i][j] = 0.f;

    for (int kb = 0; kb < 256; ++kb) {
        int k0 = (jc << 12) + (kb << 4);
        int sidx = k0 >> 8, h0 = k0 & 255;
        float4 av = *(const float4*)(hs + ((size_t)sidx * BB + row0 + lrA) * HH + h0 + lkA);
        const float* wp = Wta + (size_t)lrB * (SS * HH) + k0 + lkB;
        float4 bv0 = *(const float4*)wp;
        float4 bv1 = *(const float4*)(wp + 4);
        __syncthreads();
        As[lkA + 0][lrA] = av.x;
        As[lkA + 1][lrA] = av.y;
        As[lkA + 2][lrA] = av.z;
        As[lkA + 3][lrA] = av.w;
        Bs[lkB + 0][lrB] = bv0.x;
        Bs[lkB + 1][lrB] = bv0.y;
        Bs[lkB + 2][lrB] = bv0.z;
        Bs[lkB + 3][lrB] = bv0.w;
        Bs[lkB + 4][lrB] = bv1.x;
        Bs[lkB + 5][lrB] = bv1.y;
        Bs[lkB + 6][lrB] = bv1.z;
        Bs[lkB + 7][lrB] = bv1.w;
        __syncthreads();
#pragma unroll
        for (int k = 0; k < 16; ++k) {
            float4 af = *(const float4*)&As[k][ty << 2];
            float4 b0 = *(const float4*)&Bs[k][tx << 2];
            float4 b1 = *(const float4*)&Bs[k][64 + (tx << 2)];
            float ar[4] = {af.x, af.y, af.z, af.w};
            float br[8] = {b0.x, b0.y, b0.z, b0.w, b1.x, b1.y, b1.z, b1.w};
#pragma unroll
            for (int i = 0; i < 4; ++i)
#pragma unroll
                for (int j = 0; j < 8; ++j)
                    acc[i][j] = fmaf(ar[i], br[j], acc[i][j]);
        }
    }
#pragma unroll
    for (int i = 0; i < 4; ++i) {
        int b = row0 + (ty << 2) + i;
        float* pp = part + ((size_t)jc * BB + b) * SS;
        float4 o0 = {acc[i][0], acc[i][1], acc[i][2], acc[i][3]};
        float4 o1 = {acc[i][4], acc[i][5], acc[i][6], acc[i][7]};
        *(float4*)(pp + (tx << 2)) = o0;
        *(float4*)(pp + 64 + (tx << 2)) = o1;
    }
}

// ---- relu -> softmax -> weighted sum of q : one wave per batch row -------
__global__ __launch_bounds__(256) void attn_finalize(const float* __restrict__ part,
                                                     const float* __restrict__ b_ta,
                                                     const float* __restrict__ q,
                                                     float* __restrict__ out) {
    int wid = threadIdx.x >> 6, lane = threadIdx.x & 63;
    int b = (blockIdx.x << 2) + wid;
    float l0 = b_ta[lane], l1 = b_ta[lane + 64];
#pragma unroll
    for (int j = 0; j < 8; ++j) {
        const float* pp = part + ((size_t)j * BB + b) * SS;
        l0 += pp[lane];
        l1 += pp[lane + 64];
    }
    l0 = fmaxf(l0, 0.f);
    l1 = fmaxf(l1, 0.f);
    float mx = fmaxf(l0, l1);
#pragma unroll
    for (int off = 32; off; off >>= 1) mx = fmaxf(mx, __shfl_xor(mx, off));
    float e0 = __expf(l0 - mx), e1 = __expf(l1 - mx);
    float num = fmaf(e0, q[b * SS + lane], e1 * q[b * SS + lane + 64]);
    float den = e0 + e1;
#pragma unroll
    for (int off = 32; off; off >>= 1) {
        num += __shfl_xor(num, off);
        den += __shfl_xor(den, off);
    }
    if (lane == 0) out[b] = num / den;
}

extern "C" void kernel_launch(void* const* d_in, const int* in_sizes, int n_in,
                              void* d_out, int out_size, void* d_ws, size_t ws_size,
                              hipStream_t stream) {
    const float* x     = (const float*)d_in[0];
    const float* gamma = (const float*)d_in[1];
    const float* beta_ = (const float*)d_in[2];
    const float* W_in  = (const float*)d_in[3];
    const float* W_ih  = (const float*)d_in[4];
    const float* b_ih  = (const float*)d_in[5];
    const float* W_hh  = (const float*)d_in[6];
    const float* b_hh  = (const float*)d_in[7];
    const float* W_ta  = (const float*)d_in[8];
    const float* b_ta  = (const float*)d_in[9];
    const float* W_out = (const float*)d_in[10];
    float* out = (float*)d_out;

    float* ws = (float*)d_ws;
    float* colsum   = ws;                       // 8192
    float* colsumsq = ws + 8192;                // 8192
    float* scl      = ws + 16384;               // 8192
    float* shf      = ws + 24576;               // 8192
    float* proj     = ws + 32768;               // 4096*8192   = 33,554,432 f
    float* cbuf     = proj + 33554432;          // 4096*256    = 1,048,576 f
    float* hs       = cbuf + 1048576;           // 128*4096*256= 134,217,728 f
    float* q        = hs + 134217728;           // 4096*128
    float* part     = q + 524288;               // 8*4096*128

    // split-bf16 staging buffers alias the hs region (hs is written only
    // after gemm_mfma_split has consumed them): 201.3M ushorts < 134.2M floats
    unsigned short* xh = (unsigned short*)hs;
    unsigned short* xl = xh + (size_t)BB * INF;
    unsigned short* Wh = xl + (size_t)BB * INF;
    unsigned short* Wl = Wh + (size_t)INF * INF;

    hipMemsetAsync(colsum, 0, 2 * 8192 * sizeof(float), stream);
    bn_partial<<<dim3(32, 16), 256, 0, stream>>>(x, colsum, colsumsq);
    bn_finalize<<<32, 256, 0, stream>>>(colsum, colsumsq, gamma, beta_, scl, shf);
    split_x<<<32768, 256, 0, stream>>>(x, scl, shf, xh, xl);
    split_w<<<65536, 256, 0, stream>>>(W_in, Wh, Wl);
    gemm_mfma_split<<<dim3(64, 32), 256, 0, stream>>>(xh, xl, Wh, Wl, proj, BB, INF, INF);
    for (int s = 0; s < 128; ++s)
        lstm_step<<<dim3(4, 64), 256, 0, stream>>>(proj, W_ih, W_hh, b_ih, b_hh, cbuf, hs, s);
    q_kernel<<<131072, 256, 0, stream>>>(hs, W_out, q);
    attn_part<<<dim3(64, 8), 256, 0, stream>>>(hs, W_ta, part);
    attn_finalize<<<1024, 256, 0, stream>>>(part, b_ta, q, out);
}

// Round 3
// 5687.870 us; speedup vs baseline: 2.5686x; 1.7836x over previous
//
#include <hip/hip_runtime.h>
#include <hip/hip_bf16.h>

#define BB 4096
#define INF 8192
#define SS 128
#define HH 256

typedef __attribute__((ext_vector_type(8))) short short8;
typedef __attribute__((ext_vector_type(4))) float f32x4;

__device__ __forceinline__ float sigm(float x) { return 1.f / (1.f + __expf(-x)); }
__device__ __forceinline__ float tanh_fast(float x) {
    float cx = fminf(15.f, fmaxf(-15.f, x));
    float e = __expf(2.f * cx);
    return (e - 1.f) / (e + 1.f);
}
__device__ __forceinline__ unsigned short f2bf(float f) {
    __hip_bfloat16 b = __float2bfloat16(f);
    return *(unsigned short*)&b;
}
__device__ __forceinline__ float bf2f(unsigned short u) {
    __hip_bfloat16 b = *(__hip_bfloat16*)&u;
    return __bfloat162float(b);
}

#define GLD(g, l) __builtin_amdgcn_global_load_lds(                              \
        (const __attribute__((address_space(1))) void*)(g),                      \
        (__attribute__((address_space(3))) void*)(l), 16, 0, 0)

// ---- BatchNorm stats ------------------------------------------------------
__global__ __launch_bounds__(256) void bn_partial(const float* __restrict__ x,
                                                  float* __restrict__ colsum,
                                                  float* __restrict__ colsumsq) {
    int j = blockIdx.x * 256 + threadIdx.x;
    int r0 = blockIdx.y * 256;
    float s1 = 0.f, s2 = 0.f;
    for (int r = r0; r < r0 + 256; ++r) {
        float v = x[(size_t)r * INF + j];
        s1 += v;
        s2 += v * v;
    }
    atomicAdd(&colsum[j], s1);
    atomicAdd(&colsumsq[j], s2);
}

__global__ __launch_bounds__(256) void bn_finalize(const float* __restrict__ colsum,
                                                   const float* __restrict__ colsumsq,
                                                   const float* __restrict__ gamma,
                                                   const float* __restrict__ beta,
                                                   float* __restrict__ scl,
                                                   float* __restrict__ shf) {
    int j = blockIdx.x * 256 + threadIdx.x;
    float mean = colsum[j] * (1.f / BB);
    float var = colsumsq[j] * (1.f / BB) - mean * mean;
    float a = gamma[j] * rsqrtf(var + 1e-5f);
    scl[j] = a;
    shf[j] = beta[j] - mean * a;
}

// ---- split fp32 -> bf16 hi/lo with BN affine fused ------------------------
__global__ __launch_bounds__(256) void split_x(const float* __restrict__ x,
                                               const float* __restrict__ scl,
                                               const float* __restrict__ shf,
                                               unsigned short* __restrict__ hi,
                                               unsigned short* __restrict__ lo) {
    size_t i = ((size_t)blockIdx.x * 256 + threadIdx.x) * 4;
    float4 v = *(const float4*)(x + i);
    int col = (int)(i & (INF - 1));
    float4 s = *(const float4*)(scl + col);
    float4 h = *(const float4*)(shf + col);
    float f[4] = {fmaf(v.x, s.x, h.x), fmaf(v.y, s.y, h.y),
                  fmaf(v.z, s.z, h.z), fmaf(v.w, s.w, h.w)};
    ushort4 hv, lv;
    unsigned short* hp = (unsigned short*)&hv;
    unsigned short* lp = (unsigned short*)&lv;
#pragma unroll
    for (int k = 0; k < 4; ++k) {
        unsigned short hb = f2bf(f[k]);
        hp[k] = hb;
        lp[k] = f2bf(f[k] - bf2f(hb));
    }
    *(ushort4*)(hi + i) = hv;
    *(ushort4*)(lo + i) = lv;
}

__global__ __launch_bounds__(256) void split_w(const float* __restrict__ w,
                                               unsigned short* __restrict__ hi,
                                               unsigned short* __restrict__ lo) {
    size_t i = ((size_t)blockIdx.x * 256 + threadIdx.x) * 4;
    float4 v = *(const float4*)(w + i);
    float f[4] = {v.x, v.y, v.z, v.w};
    ushort4 hv, lv;
    unsigned short* hp = (unsigned short*)&hv;
    unsigned short* lp = (unsigned short*)&lv;
#pragma unroll
    for (int k = 0; k < 4; ++k) {
        unsigned short hb = f2bf(f[k]);
        hp[k] = hb;
        lp[k] = f2bf(f[k] - bf2f(hb));
    }
    *(ushort4*)(hi + i) = hv;
    *(ushort4*)(lo + i) = lv;
}

// ---- pack W_ih|W_hh into gate-interleaved rows + split --------------------
// Wcat row r (r=4*hcol+gate): cols 0..63 = W_ih[gate*256+hcol], 64..319 = W_hh row.
__global__ __launch_bounds__(128) void pack_w(const float* __restrict__ Wih,
                                              const float* __restrict__ Whh,
                                              const float* __restrict__ bih,
                                              const float* __restrict__ bhh,
                                              unsigned short* __restrict__ Wch,
                                              unsigned short* __restrict__ Wcl,
                                              float* __restrict__ biascat) {
    int r = blockIdx.x;  // 0..1023
    int c = r >> 2, g = r & 3;
    int t = threadIdx.x;
    if (t == 0) biascat[r] = bih[g * 256 + c] + bhh[g * 256 + c];
    if (t >= 80) return;
    float4 v;
    if (t < 16)
        v = *(const float4*)(Wih + (size_t)(g * 256 + c) * 64 + t * 4);
    else
        v = *(const float4*)(Whh + (size_t)(g * 256 + c) * 256 + (t - 16) * 4);
    float f[4] = {v.x, v.y, v.z, v.w};
    ushort4 hv, lv;
    unsigned short* hp = (unsigned short*)&hv;
    unsigned short* lp = (unsigned short*)&lv;
#pragma unroll
    for (int k = 0; k < 4; ++k) {
        unsigned short hb = f2bf(f[k]);
        hp[k] = hb;
        lp[k] = f2bf(f[k] - bf2f(hb));
    }
    *(ushort4*)(Wch + (size_t)r * 320 + t * 4) = hv;
    *(ushort4*)(Wcl + (size_t)r * 320 + t * 4) = lv;
}

// ---- big GEMM: proj = xn @ W_in^T, split-bf16 MFMA, writes proj as bf16
// hi/lo in slice-major layout: slice s (64 cols) -> ps = projsplit + s*524288;
// hi at ps[row*64+c], lo at ps[262144 + row*64+c].
// LDS XOR swizzle: (row,k) stored at slot row*4 + (k ^ ((row>>1)&3)).
__global__ __launch_bounds__(256) void gemm_mfma_split(
    const unsigned short* __restrict__ Ah, const unsigned short* __restrict__ Al,
    const unsigned short* __restrict__ Bh, const unsigned short* __restrict__ Bl,
    unsigned short* __restrict__ projsplit, int K) {
    __shared__ unsigned short AsH[4096], AsL[4096], BsH[4096], BsL[4096];
    const int tid = threadIdx.x;
    const int lane = tid & 63, wid = tid >> 6;
    // L2 supertile swizzle: 16x16 block groups (grid 64x32 tiles)
    int bid = blockIdx.x;
    int grp = bid >> 8, loc = bid & 255;
    int bx = ((grp & 3) << 4) | (loc & 15);
    int by = ((grp >> 2) << 4) | (loc >> 4);
    const int row0 = by << 7, col0 = bx << 7;
    const int wm = (wid & 1) << 6, wn = (wid >> 1) << 6;
    const int q = lane >> 4, l15 = lane & 15;

    const int s0 = wid * 128 + lane, s1 = s0 + 64;
    const int r0 = s0 >> 2, k0 = (((s0 & 3) ^ ((r0 >> 1) & 3)) << 3);
    const int r1 = s1 >> 2, k1 = (((s1 & 3) ^ ((r1 >> 1) & 3)) << 3);
    const size_t aoff0 = (size_t)(row0 + r0) * K + k0;
    const size_t aoff1 = (size_t)(row0 + r1) * K + k1;
    const size_t boff0 = (size_t)(col0 + r0) * K + k0;
    const size_t boff1 = (size_t)(col0 + r1) * K + k1;
    const int lb0 = (wid * 128) * 8, lb1 = lb0 + 512;

    f32x4 acc[4][4];
#pragma unroll
    for (int i = 0; i < 4; ++i)
#pragma unroll
        for (int j = 0; j < 4; ++j) acc[i][j] = (f32x4){0.f, 0.f, 0.f, 0.f};

    for (int kb = 0; kb < K; kb += 32) {
        __syncthreads();
        GLD(Ah + aoff0 + kb, &AsH[lb0]);
        GLD(Ah + aoff1 + kb, &AsH[lb1]);
        GLD(Al + aoff0 + kb, &AsL[lb0]);
        GLD(Al + aoff1 + kb, &AsL[lb1]);
        GLD(Bh + boff0 + kb, &BsH[lb0]);
        GLD(Bh + boff1 + kb, &BsH[lb1]);
        GLD(Bl + boff0 + kb, &BsL[lb0]);
        GLD(Bl + boff1 + kb, &BsL[lb1]);
        __syncthreads();

        short8 ahf[4], alf[4], bhf[4], blf[4];
#pragma unroll
        for (int i = 0; i < 4; ++i) {
            int ra = wm + i * 16 + l15;
            int offa = ra * 32 + ((q ^ ((ra >> 1) & 3)) << 3);
            ahf[i] = *(const short8*)&AsH[offa];
            alf[i] = *(const short8*)&AsL[offa];
            int rb = wn + i * 16 + l15;
            int offb = rb * 32 + ((q ^ ((rb >> 1) & 3)) << 3);
            bhf[i] = *(const short8*)&BsH[offb];
            blf[i] = *(const short8*)&BsL[offb];
        }
#pragma unroll
        for (int i = 0; i < 4; ++i)
#pragma unroll
            for (int j = 0; j < 4; ++j) {
                acc[i][j] = __builtin_amdgcn_mfma_f32_16x16x32_bf16(ahf[i], bhf[j], acc[i][j], 0, 0, 0);
                acc[i][j] = __builtin_amdgcn_mfma_f32_16x16x32_bf16(ahf[i], blf[j], acc[i][j], 0, 0, 0);
                acc[i][j] = __builtin_amdgcn_mfma_f32_16x16x32_bf16(alf[i], bhf[j], acc[i][j], 0, 0, 0);
            }
    }

#pragma unroll
    for (int i = 0; i < 4; ++i)
#pragma unroll
        for (int j = 0; j < 4; ++j) {
            int col = col0 + wn + j * 16 + l15;
            int slice = col >> 6, c6 = col & 63;
            unsigned short* ps = projsplit + (size_t)slice * 524288;
#pragma unroll
            for (int r = 0; r < 4; ++r) {
                int row = row0 + wm + i * 16 + q * 4 + r;
                float v = acc[i][j][r];
                unsigned short hb = f2bf(v);
                ps[row * 64 + c6] = hb;
                ps[262144 + row * 64 + c6] = f2bf(v - bf2f(hb));
            }
        }
}

// ---- one LSTM step: M=4096 x N=1024 gates GEMM (K=320) + fused cell ------
// grid 256 = 32 row-tiles x 8 col-tiles; block = 128 rows x 128 gate-cols
// (= 32 hidden cols x 4 interleaved gates).
__global__ __launch_bounds__(256) void lstm_step_mfma(
    const unsigned short* __restrict__ projsplit,
    const unsigned short* __restrict__ Wch, const unsigned short* __restrict__ Wcl,
    const float* __restrict__ biascat,
    const unsigned short* __restrict__ hin_h, const unsigned short* __restrict__ hin_l,
    unsigned short* __restrict__ hout_h, unsigned short* __restrict__ hout_l,
    float* __restrict__ cbuf, float* __restrict__ hs, int s) {
    __shared__ unsigned short AsH[4096], AsL[4096], BsH[4096], BsL[4096];
    __shared__ float gates[128][132];
    __shared__ float sbias[128];
    const int tid = threadIdx.x;
    const int lane = tid & 63, wid = tid >> 6;
    const int row0 = (blockIdx.x & 31) << 7;
    const int col0 = (blockIdx.x >> 5) << 7;
    if (tid < 128) sbias[tid] = biascat[col0 + tid];

    const int wm = (wid & 1) << 6, wn = (wid >> 1) << 6;
    const int q = lane >> 4, l15 = lane & 15;
    const int s0 = wid * 128 + lane, s1 = s0 + 64;
    const int r0 = s0 >> 2, k0 = (((s0 & 3) ^ ((r0 >> 1) & 3)) << 3);
    const int r1 = s1 >> 2, k1 = (((s1 & 3) ^ ((r1 >> 1) & 3)) << 3);
    const int lb0 = (wid * 128) * 8, lb1 = lb0 + 512;

    const unsigned short* psl = projsplit + (size_t)s * 524288;

    f32x4 acc[4][4];
#pragma unroll
    for (int i = 0; i < 4; ++i)
#pragma unroll
        for (int j = 0; j < 4; ++j) acc[i][j] = (f32x4){0.f, 0.f, 0.f, 0.f};

    for (int kb = 0; kb < 10; ++kb) {
        __syncthreads();
        const unsigned short *pah0, *pal0, *pah1, *pal1;
        if (kb < 2) {
            int off0 = (row0 + r0) * 64 + kb * 32 + k0;
            int off1 = (row0 + r1) * 64 + kb * 32 + k1;
            pah0 = psl + off0;          pal0 = psl + 262144 + off0;
            pah1 = psl + off1;          pal1 = psl + 262144 + off1;
        } else {
            int kh = kb * 32 - 64;
            int off0 = (row0 + r0) * HH + kh + k0;
            int off1 = (row0 + r1) * HH + kh + k1;
            pah0 = hin_h + off0;        pal0 = hin_l + off0;
            pah1 = hin_h + off1;        pal1 = hin_l + off1;
        }
        const unsigned short* pbh0 = Wch + (size_t)(col0 + r0) * 320 + kb * 32 + k0;
        const unsigned short* pbh1 = Wch + (size_t)(col0 + r1) * 320 + kb * 32 + k1;
        const unsigned short* pbl0 = Wcl + (size_t)(col0 + r0) * 320 + kb * 32 + k0;
        const unsigned short* pbl1 = Wcl + (size_t)(col0 + r1) * 320 + kb * 32 + k1;
        GLD(pah0, &AsH[lb0]);
        GLD(pah1, &AsH[lb1]);
        GLD(pal0, &AsL[lb0]);
        GLD(pal1, &AsL[lb1]);
        GLD(pbh0, &BsH[lb0]);
        GLD(pbh1, &BsH[lb1]);
        GLD(pbl0, &BsL[lb0]);
        GLD(pbl1, &BsL[lb1]);
        __syncthreads();

        short8 ahf[4], alf[4], bhf[4], blf[4];
#pragma unroll
        for (int i = 0; i < 4; ++i) {
            int ra = wm + i * 16 + l15;
            int offa = ra * 32 + ((q ^ ((ra >> 1) & 3)) << 3);
            ahf[i] = *(const short8*)&AsH[offa];
            alf[i] = *(const short8*)&AsL[offa];
            int rb = wn + i * 16 + l15;
            int offb = rb * 32 + ((q ^ ((rb >> 1) & 3)) << 3);
            bhf[i] = *(const short8*)&BsH[offb];
            blf[i] = *(const short8*)&BsL[offb];
        }
#pragma unroll
        for (int i = 0; i < 4; ++i)
#pragma unroll
            for (int j = 0; j < 4; ++j) {
                acc[i][j] = __builtin_amdgcn_mfma_f32_16x16x32_bf16(ahf[i], bhf[j], acc[i][j], 0, 0, 0);
                acc[i][j] = __builtin_amdgcn_mfma_f32_16x16x32_bf16(ahf[i], blf[j], acc[i][j], 0, 0, 0);
                acc[i][j] = __builtin_amdgcn_mfma_f32_16x16x32_bf16(alf[i], bhf[j], acc[i][j], 0, 0, 0);
            }
    }

    // gates -> LDS (acc layout: row = wm+i*16+q*4+r, col = wn+j*16+l15)
    __syncthreads();
#pragma unroll
    for (int i = 0; i < 4; ++i)
#pragma unroll
        for (int j = 0; j < 4; ++j)
#pragma unroll
            for (int r = 0; r < 4; ++r)
                gates[wm + i * 16 + q * 4 + r][wn + j * 16 + l15] = acc[i][j][r];
    __syncthreads();

    // fused cell update: thread -> hidden col hc (0..31), rows rg*16..+15
    const int hc = tid & 31, rg = tid >> 5;
    const int hbase = col0 >> 2;  // global hidden col base (32 per block)
#pragma unroll
    for (int rr = 0; rr < 16; ++rr) {
        int row = rg * 16 + rr;
        int b = row0 + row;
        float4 g4 = *(const float4*)&gates[row][4 * hc];
        float4 b4 = *(const float4*)&sbias[4 * hc];
        size_t ci = (size_t)b * HH + hbase + hc;
        float cold = (s > 0) ? cbuf[ci] : 0.f;
        float i_ = sigm(g4.x + b4.x);
        float f_ = sigm(g4.y + b4.y);
        float g_ = tanh_fast(g4.z + b4.z);
        float o_ = sigm(g4.w + b4.w);
        float cn = fmaf(f_, cold, i_ * g_);
        float hn = o_ * tanh_fast(cn);
        cbuf[ci] = cn;
        hs[(size_t)s * (BB * HH) + ci] = hn;
        unsigned short hb = f2bf(hn);
        hout_h[ci] = hb;
        hout_l[ci] = f2bf(hn - bf2f(hb));
    }
}

// ---- q[b,s] = hs[s,b,:] . W_out ------------------------------------------
__global__ __launch_bounds__(256) void q_kernel(const float* __restrict__ hs,
                                                const float* __restrict__ wout,
                                                float* __restrict__ q) {
    int wid = threadIdx.x >> 6, lane = threadIdx.x & 63;
    int p = (blockIdx.x << 2) + wid;
    int b = p & (BB - 1), s = p >> 12;
    const float* hp = hs + ((size_t)s * BB + b) * HH + (lane << 2);
    float4 h4 = *(const float4*)hp;
    float4 w4 = *(const float4*)(wout + (lane << 2));
    float v = h4.x * w4.x + h4.y * w4.y + h4.z * w4.z + h4.w * w4.w;
#pragma unroll
    for (int off = 32; off; off >>= 1) v += __shfl_xor(v, off);
    if (lane == 0) q[b * SS + s] = v;
}

// ---- attention logits, split-K (8 chunks of K=4096) ----------------------
__global__ __launch_bounds__(256) void attn_part(const float* __restrict__ hs,
                                                 const float* __restrict__ Wta,
                                                 float* __restrict__ part) {
    __shared__ float As[16][68];
    __shared__ float Bs[16][132];
    const int tid = threadIdx.x;
    const int tx = tid & 15, ty = tid >> 4;
    const int row0 = blockIdx.x << 6;
    const int jc = blockIdx.y;
    const int lrA = tid >> 2, lkA = (tid & 3) << 2;
    const int lrB = tid >> 1, lkB = (tid & 1) << 3;

    float acc[4][8];
#pragma unroll
    for (int i = 0; i < 4; ++i)
#pragma unroll
        for (int j = 0; j < 8; ++j) acc[i][j] = 0.f;

    for (int kb = 0; kb < 256; ++kb) {
        int k0 = (jc << 12) + (kb << 4);
        int sidx = k0 >> 8, h0 = k0 & 255;
        float4 av = *(const float4*)(hs + ((size_t)sidx * BB + row0 + lrA) * HH + h0 + lkA);
        const float* wp = Wta + (size_t)lrB * (SS * HH) + k0 + lkB;
        float4 bv0 = *(const float4*)wp;
        float4 bv1 = *(const float4*)(wp + 4);
        __syncthreads();
        As[lkA + 0][lrA] = av.x;
        As[lkA + 1][lrA] = av.y;
        As[lkA + 2][lrA] = av.z;
        As[lkA + 3][lrA] = av.w;
        Bs[lkB + 0][lrB] = bv0.x;
        Bs[lkB + 1][lrB] = bv0.y;
        Bs[lkB + 2][lrB] = bv0.z;
        Bs[lkB + 3][lrB] = bv0.w;
        Bs[lkB + 4][lrB] = bv1.x;
        Bs[lkB + 5][lrB] = bv1.y;
        Bs[lkB + 6][lrB] = bv1.z;
        Bs[lkB + 7][lrB] = bv1.w;
        __syncthreads();
#pragma unroll
        for (int k = 0; k < 16; ++k) {
            float4 af = *(const float4*)&As[k][ty << 2];
            float4 b0 = *(const float4*)&Bs[k][tx << 2];
            float4 b1 = *(const float4*)&Bs[k][64 + (tx << 2)];
            float ar[4] = {af.x, af.y, af.z, af.w};
            float br[8] = {b0.x, b0.y, b0.z, b0.w, b1.x, b1.y, b1.z, b1.w};
#pragma unroll
            for (int i = 0; i < 4; ++i)
#pragma unroll
                for (int j = 0; j < 8; ++j)
                    acc[i][j] = fmaf(ar[i], br[j], acc[i][j]);
        }
    }
#pragma unroll
    for (int i = 0; i < 4; ++i) {
        int b = row0 + (ty << 2) + i;
        float* pp = part + ((size_t)jc * BB + b) * SS;
        float4 o0 = {acc[i][0], acc[i][1], acc[i][2], acc[i][3]};
        float4 o1 = {acc[i][4], acc[i][5], acc[i][6], acc[i][7]};
        *(float4*)(pp + (tx << 2)) = o0;
        *(float4*)(pp + 64 + (tx << 2)) = o1;
    }
}

// ---- relu -> softmax -> weighted sum of q --------------------------------
__global__ __launch_bounds__(256) void attn_finalize(const float* __restrict__ part,
                                                     const float* __restrict__ b_ta,
                                                     const float* __restrict__ q,
                                                     float* __restrict__ out) {
    int wid = threadIdx.x >> 6, lane = threadIdx.x & 63;
    int b = (blockIdx.x << 2) + wid;
    float l0 = b_ta[lane], l1 = b_ta[lane + 64];
#pragma unroll
    for (int j = 0; j < 8; ++j) {
        const float* pp = part + ((size_t)j * BB + b) * SS;
        l0 += pp[lane];
        l1 += pp[lane + 64];
    }
    l0 = fmaxf(l0, 0.f);
    l1 = fmaxf(l1, 0.f);
    float mx = fmaxf(l0, l1);
#pragma unroll
    for (int off = 32; off; off >>= 1) mx = fmaxf(mx, __shfl_xor(mx, off));
    float e0 = __expf(l0 - mx), e1 = __expf(l1 - mx);
    float num = fmaf(e0, q[b * SS + lane], e1 * q[b * SS + lane + 64]);
    float den = e0 + e1;
#pragma unroll
    for (int off = 32; off; off >>= 1) {
        num += __shfl_xor(num, off);
        den += __shfl_xor(den, off);
    }
    if (lane == 0) out[b] = num / den;
}

extern "C" void kernel_launch(void* const* d_in, const int* in_sizes, int n_in,
                              void* d_out, int out_size, void* d_ws, size_t ws_size,
                              hipStream_t stream) {
    const float* x     = (const float*)d_in[0];
    const float* gamma = (const float*)d_in[1];
    const float* beta_ = (const float*)d_in[2];
    const float* W_in  = (const float*)d_in[3];
    const float* W_ih  = (const float*)d_in[4];
    const float* b_ih  = (const float*)d_in[5];
    const float* W_hh  = (const float*)d_in[6];
    const float* b_hh  = (const float*)d_in[7];
    const float* W_ta  = (const float*)d_in[8];
    const float* b_ta  = (const float*)d_in[9];
    const float* W_out = (const float*)d_in[10];
    float* out = (float*)d_out;

    float* ws = (float*)d_ws;
    // --- small region (float offsets) ---
    float* colsum   = ws;                 // 8192
    float* colsumsq = ws + 8192;          // 8192
    float* scl      = ws + 16384;         // 8192
    float* shf      = ws + 24576;         // 8192
    float* biascat  = ws + 32768;         // 1024
    float* qbuf     = ws + 33792;         // 524288
    float* part     = ws + 558080;        // 8*4096*128 = 4194304
    float* cbuf     = ws + 4752384;       // 1048576
    unsigned short* Wch   = (unsigned short*)(ws + 5800960);  // 327680 us
    unsigned short* Wcl   = (unsigned short*)(ws + 5964800);  // 327680 us
    unsigned short* hsp0h = (unsigned short*)(ws + 6128640);  // 1048576 us
    unsigned short* hsp0l = (unsigned short*)(ws + 6652928);
    unsigned short* hsp1h = (unsigned short*)(ws + 7177216);
    unsigned short* hsp1l = (unsigned short*)(ws + 7701504);  // ends 8225792
    // --- hs region (537 MB) + aliased transients ---
    float* hs = ws + 8388608;             // 128*4096*256 floats
    // phase-1 aliases inside hs region (dead before first hs write):
    unsigned short* xh = (unsigned short*)hs;        // 33554432 us
    unsigned short* xl = xh + 33554432;
    unsigned short* Wh = xl + 33554432;              // 67108864 us
    unsigned short* Wl = Wh + 67108864;              // ends at +384 MiB
    // proj split, slice-major, above the tail of hs (disjoint from hs slab s
    // for all steps: base 432,013,312 B + s*1,048,576 >= (s+1)*4,194,304):
    unsigned short* projsplit = (unsigned short*)(ws + 8388608 + 108003328);

    hipMemsetAsync(colsum, 0, 2 * 8192 * sizeof(float), stream);
    hipMemsetAsync(hsp0h, 0, 4194304, stream);  // hsp0h+hsp0l (h at s=0 is 0)

    bn_partial<<<dim3(32, 16), 256, 0, stream>>>(x, colsum, colsumsq);
    bn_finalize<<<32, 256, 0, stream>>>(colsum, colsumsq, gamma, beta_, scl, shf);
    split_x<<<32768, 256, 0, stream>>>(x, scl, shf, xh, xl);
    split_w<<<65536, 256, 0, stream>>>(W_in, Wh, Wl);
    pack_w<<<1024, 128, 0, stream>>>(W_ih, W_hh, b_ih, b_hh, Wch, Wcl, biascat);
    gemm_mfma_split<<<2048, 256, 0, stream>>>(xh, xl, Wh, Wl, projsplit, INF);
    for (int s = 0; s < 128; ++s) {
        const unsigned short* hih = (s & 1) ? hsp1h : hsp0h;
        const unsigned short* hil = (s & 1) ? hsp1l : hsp0l;
        unsigned short* hoh = (s & 1) ? hsp0h : hsp1h;
        unsigned short* hol = (s & 1) ? hsp0l : hsp1l;
        lstm_step_mfma<<<256, 256, 0, stream>>>(projsplit, Wch, Wcl, biascat,
                                                hih, hil, hoh, hol, cbuf, hs, s);
    }
    q_kernel<<<131072, 256, 0, stream>>>(hs, W_out, qbuf);
    attn_part<<<dim3(64, 8), 256, 0, stream>>>(hs, W_ta, part);
    attn_finalize<<<1024, 256, 0, stream>>>(part, b_ta, qbuf, out);
}